// Round 3
// baseline (270.367 us; speedup 1.0000x reference)
//
#include <hip/hip_runtime.h>
#include <hip/hip_bf16.h>
#include <cstdint>

typedef __bf16 bf16x8 __attribute__((ext_vector_type(8)));
typedef float f32x4 __attribute__((ext_vector_type(4)));

// ---------- helpers ----------
__device__ __forceinline__ unsigned short f2bf(float f) {
  union { float f; uint32_t u; } a; a.f = f;
  uint32_t r = a.u + 0x7fffu + ((a.u >> 16) & 1u);
  return (unsigned short)(r >> 16);
}
__device__ __forceinline__ float bf2f(unsigned short b) {
  union { uint32_t u; float f; } a; a.u = ((uint32_t)b) << 16;
  return a.f;
}
__device__ __forceinline__ void gload_lds16(const unsigned short* g, unsigned short* l) {
  __builtin_amdgcn_global_load_lds(
      (const __attribute__((address_space(1))) void*)g,
      (__attribute__((address_space(3))) void*)l, 16, 0, 0);
}

// ---------- cast kernels ----------
__global__ void cast_x_kernel(const float* __restrict__ x, unsigned short* __restrict__ xb) {
  size_t i = ((size_t)blockIdx.x * 256 + threadIdx.x) * 8;
  float4 a = *(const float4*)(x + i);
  float4 b = *(const float4*)(x + i + 4);
  uint4 o;
  o.x = (uint32_t)f2bf(a.x) | ((uint32_t)f2bf(a.y) << 16);
  o.y = (uint32_t)f2bf(a.z) | ((uint32_t)f2bf(a.w) << 16);
  o.z = (uint32_t)f2bf(b.x) | ((uint32_t)f2bf(b.y) << 16);
  o.w = (uint32_t)f2bf(b.z) | ((uint32_t)f2bf(b.w) << 16);
  *(uint4*)(xb + i) = o;
}

// W[3][1024][1024] fp32 -> Wt[3][e][d] bf16 (transpose last two dims).
__global__ void cast_w_kernel(const float* __restrict__ W, unsigned short* __restrict__ Wt) {
  __shared__ float tile[32][33];
  const int z = blockIdx.z;
  const float* Wz = W + (size_t)z * 1024 * 1024;
  unsigned short* Wtz = Wt + (size_t)z * 1024 * 1024;
  const int x0 = blockIdx.x * 32, y0 = blockIdx.y * 32;
  const int tx = threadIdx.x, ty = threadIdx.y;
#pragma unroll
  for (int i = 0; i < 32; i += 8)
    tile[ty + i][tx] = Wz[(size_t)(y0 + ty + i) * 1024 + x0 + tx];
  __syncthreads();
#pragma unroll
  for (int i = 0; i < 32; i += 8)
    Wtz[(size_t)(x0 + ty + i) * 1024 + y0 + tx] = f2bf(tile[tx][ty + i]);
}

// ---------- GEMM: C[m,n] = scale * sum_k A[m,k] * Bt[n,k] ----------
// Tiles 128x128, BK=32, DOUBLE-BUFFERED: one barrier per K-step; loads for
// step k+1 issued right after the barrier, before compute on step k, so the
// vmcnt(0) drain at the next barrier has a full compute phase in flight.
// LDS layout per buf: [row 0..127][chunk 0..3] of 16B chunks, swizzled
//   LDS(row,c) = global chunk (c ^ ((row>>1)&3))  -> 2-way banks max (free).
// MODE: 0 = bf16 store (w/ scale), 3 = f32 store,
//       4 = merged QKV: z=0,1 -> bf16 to Call + z*sC; z=2 -> transposed
//           bf16 store Vt[b][e=n][s] (m = b*2048+s).
template <int MODE>
__global__ void __launch_bounds__(256)
gemm_bt(const unsigned short* __restrict__ Aall,
        const unsigned short* __restrict__ Btall,
        void* __restrict__ Call, unsigned short* __restrict__ VtPtr,
        int K, int ldc, long sA, long sB, long sC, float scale) {
  __shared__ unsigned short As[2][4096];
  __shared__ unsigned short Bs[2][4096];
  const int t = threadIdx.x;
  const int lane = t & 63;
  const int quad = lane >> 4;
  const int l15 = lane & 15;
  const int wave = t >> 6;
  const int wm = (wave >> 1) * 64;
  const int wn = (wave & 1) * 64;
  const int z = blockIdx.z;

  const unsigned short* A = Aall + (size_t)z * sA + (size_t)blockIdx.x * 128 * K;
  const unsigned short* Bt = Btall + (size_t)z * sB + (size_t)blockIdx.y * 128 * K;

  // staging: call0 -> LDS chunk t (row t>>2, chunk t&3); call1 -> +64 rows.
  // source chunk swizzle: c ^ ((row>>1)&3); (row+64)>>1 keeps bits 1:0 -> same.
  const int srow = t >> 2;                             // 0..63
  const int scol = (((t & 3) ^ ((srow >> 1) & 3)) * 8);
  const unsigned short* ga = A + (size_t)srow * K + scol;
  const unsigned short* gb = Bt + (size_t)srow * K + scol;
  const size_t rowskip = (size_t)64 * K;

  // fragment read: row = w? + 16i + l15, chunk = quad ^ ((l15>>1)&3)
  const int aOff = (wm + l15) * 32 + (quad ^ ((l15 >> 1) & 3)) * 8;
  const int bOff = (wn + l15) * 32 + (quad ^ ((l15 >> 1) & 3)) * 8;

  f32x4 acc[4][4];
#pragma unroll
  for (int i = 0; i < 4; i++)
#pragma unroll
    for (int j = 0; j < 4; j++) acc[i][j] = (f32x4){0.f, 0.f, 0.f, 0.f};

  // prologue: stage k0=0 into buf 0
  gload_lds16(ga, &As[0][t * 8]);
  gload_lds16(ga + rowskip, &As[0][2048 + t * 8]);
  gload_lds16(gb, &Bs[0][t * 8]);
  gload_lds16(gb + rowskip, &Bs[0][2048 + t * 8]);

  int buf = 0;
  for (int k0 = 0; k0 < K; k0 += 32, buf ^= 1) {
    __syncthreads();  // drains vmcnt -> buf ready; all reads of buf^1 done
    if (k0 + 32 < K) {
      const int kn = k0 + 32;
      gload_lds16(ga + kn, &As[buf ^ 1][t * 8]);
      gload_lds16(ga + rowskip + kn, &As[buf ^ 1][2048 + t * 8]);
      gload_lds16(gb + kn, &Bs[buf ^ 1][t * 8]);
      gload_lds16(gb + rowskip + kn, &Bs[buf ^ 1][2048 + t * 8]);
    }
    const unsigned short* aB = &As[buf][aOff];
    const unsigned short* bB = &Bs[buf][bOff];
    bf16x8 a[4], b[4];
#pragma unroll
    for (int i = 0; i < 4; i++) a[i] = *(const bf16x8*)(aB + i * 512);
#pragma unroll
    for (int j = 0; j < 4; j++) b[j] = *(const bf16x8*)(bB + j * 512);
#pragma unroll
    for (int i = 0; i < 4; i++)
#pragma unroll
      for (int j = 0; j < 4; j++)
        acc[i][j] = __builtin_amdgcn_mfma_f32_16x16x32_bf16(a[i], b[j], acc[i][j], 0, 0, 0);
  }

  // C/D layout: col = lane&15, row = quad*4 + reg  [verified m89/m91]
  const int mbase = blockIdx.x * 128 + wm + quad * 4;
  const int nbase = blockIdx.y * 128 + wn + l15;

  if (MODE == 0 || (MODE == 4 && z < 2)) {
    unsigned short* C = (unsigned short*)Call + (size_t)z * sC;
#pragma unroll
    for (int mi = 0; mi < 4; mi++)
#pragma unroll
      for (int ni = 0; ni < 4; ni++) {
        const int m = mbase + mi * 16, n = nbase + ni * 16;
#pragma unroll
        for (int r = 0; r < 4; r++)
          C[(size_t)(m + r) * ldc + n] = f2bf(acc[mi][ni][r] * scale);
      }
  } else if (MODE == 3) {
    float* C = (float*)Call + (size_t)z * sC;
#pragma unroll
    for (int mi = 0; mi < 4; mi++)
#pragma unroll
      for (int ni = 0; ni < 4; ni++) {
        const int m = mbase + mi * 16, n = nbase + ni * 16;
#pragma unroll
        for (int r = 0; r < 4; r++)
          C[(size_t)(m + r) * ldc + n] = acc[mi][ni][r];
      }
  } else {  // MODE 4, z==2: Vt[b][e=n][s] <- acc, m = b*2048 + s
    unsigned short* C = VtPtr;
#pragma unroll
    for (int mi = 0; mi < 4; mi++) {
      const int m = mbase + mi * 16;
      const int b = m >> 11, s = m & 2047;
#pragma unroll
      for (int ni = 0; ni < 4; ni++) {
        const int n = nbase + ni * 16;
        uint2 val;
        val.x = (uint32_t)f2bf(acc[mi][ni][0]) | ((uint32_t)f2bf(acc[mi][ni][1]) << 16);
        val.y = (uint32_t)f2bf(acc[mi][ni][2]) | ((uint32_t)f2bf(acc[mi][ni][3]) << 16);
        *(uint2*)(C + (size_t)b * 2097152 + (size_t)n * 2048 + s) = val;
      }
    }
  }
}

// ---------- row softmax, in place, bf16 [rows=8192, len=2048] ----------
__global__ void softmax_kernel(unsigned short* __restrict__ S) {
  __shared__ float redmax[4];
  __shared__ float redsum[4];
  const size_t row = blockIdx.x;
  unsigned short* p = S + row * 2048;
  const int t = threadIdx.x;
  uint4 raw = *(const uint4*)(p + t * 8);
  const unsigned short* up = (const unsigned short*)&raw;
  float v[8];
#pragma unroll
  for (int i = 0; i < 8; i++) v[i] = bf2f(up[i]);
  float m = v[0];
#pragma unroll
  for (int i = 1; i < 8; i++) m = fmaxf(m, v[i]);
#pragma unroll
  for (int off = 32; off > 0; off >>= 1) m = fmaxf(m, __shfl_xor(m, off));
  if ((t & 63) == 0) redmax[t >> 6] = m;
  __syncthreads();
  m = fmaxf(fmaxf(redmax[0], redmax[1]), fmaxf(redmax[2], redmax[3]));
  float s = 0.f;
#pragma unroll
  for (int i = 0; i < 8; i++) { v[i] = __expf(v[i] - m); s += v[i]; }
#pragma unroll
  for (int off = 32; off > 0; off >>= 1) s += __shfl_xor(s, off);
  if ((t & 63) == 0) redsum[t >> 6] = s;
  __syncthreads();
  s = redsum[0] + redsum[1] + redsum[2] + redsum[3];
  const float inv = 1.f / s;
  uint4 o;
  o.x = (uint32_t)f2bf(v[0] * inv) | ((uint32_t)f2bf(v[1] * inv) << 16);
  o.y = (uint32_t)f2bf(v[2] * inv) | ((uint32_t)f2bf(v[3] * inv) << 16);
  o.z = (uint32_t)f2bf(v[4] * inv) | ((uint32_t)f2bf(v[5] * inv) << 16);
  o.w = (uint32_t)f2bf(v[6] * inv) | ((uint32_t)f2bf(v[7] * inv) << 16);
  *(uint4*)(p + t * 8) = o;
}

// ---------- launcher ----------
// B=4, S=2048, D=1024. Workspace (102 MB):
//   xb @0: 16MB | Wt @16MB: 6MB | Q @22MB: 16MB | K @38MB: 16MB
//   Vt @54MB: 16MB [4][e][s] | Sb @70MB: 32MB scores/P [4][2048][2048]
extern "C" void kernel_launch(void* const* d_in, const int* in_sizes, int n_in,
                              void* d_out, int out_size, void* d_ws, size_t ws_size,
                              hipStream_t stream) {
  const float* x = (const float*)d_in[0];
  const float* W = (const float*)d_in[1];
  float* out = (float*)d_out;
  char* ws = (char*)d_ws;
  unsigned short* xb = (unsigned short*)(ws);
  unsigned short* Wt = (unsigned short*)(ws + (16ll << 20));
  unsigned short* Q  = (unsigned short*)(ws + (22ll << 20));
  unsigned short* Kb = (unsigned short*)(ws + (38ll << 20));
  unsigned short* Vt = (unsigned short*)(ws + (54ll << 20));
  unsigned short* Sb = (unsigned short*)(ws + (70ll << 20));

  cast_x_kernel<<<4096, 256, 0, stream>>>(x, xb);
  cast_w_kernel<<<dim3(32, 32, 3), dim3(32, 8), 0, stream>>>(W, Wt);

  // merged QKV projection: z=0 -> Q, z=1 -> K, z=2 -> Vt (transposed store)
  gemm_bt<4><<<dim3(64, 8, 3), 256, 0, stream>>>(
      xb, Wt, Q, Vt, 1024, 1024, 0L, 1048576L, 8388608L, 1.0f);
  // scores = Q K^T / 32, bf16, per batch
  gemm_bt<0><<<dim3(16, 16, 4), 256, 0, stream>>>(
      Q, Kb, Sb, nullptr, 1024, 2048, 2097152L, 2097152L, 4194304L, 0.03125f);
  // softmax rows in place
  softmax_kernel<<<8192, 256, 0, stream>>>(Sb);
  // out = P @ V  (fp32 store to d_out)
  gemm_bt<3><<<dim3(16, 8, 4), 256, 0, stream>>>(
      Sb, Vt, out, nullptr, 2048, 1024, 4194304L, 2097152L, 2097152L, 1.0f);
}

// Round 4
// 263.399 us; speedup vs baseline: 1.0265x; 1.0265x over previous
//
#include <hip/hip_runtime.h>
#include <hip/hip_bf16.h>
#include <cstdint>

typedef __bf16 bf16x8 __attribute__((ext_vector_type(8)));
typedef float f32x4 __attribute__((ext_vector_type(4)));

// ---------- helpers ----------
__device__ __forceinline__ unsigned short f2bf(float f) {
  union { float f; uint32_t u; } a; a.f = f;
  uint32_t r = a.u + 0x7fffu + ((a.u >> 16) & 1u);
  return (unsigned short)(r >> 16);
}
__device__ __forceinline__ void gload_lds16(const unsigned short* g, unsigned short* l) {
  __builtin_amdgcn_global_load_lds(
      (const __attribute__((address_space(1))) void*)g,
      (__attribute__((address_space(3))) void*)l, 16, 0, 0);
}

// ---------- merged cast kernel ----------
// blocks 0..4095: x fp32 -> bf16 (8 elems/thread)
// blocks 4096..7167: W[3][1024][1024] fp32 -> Wt[3][e][d] bf16 (transpose)
__global__ void cast_all(const float* __restrict__ x, const float* __restrict__ W,
                         unsigned short* __restrict__ xb, unsigned short* __restrict__ Wt) {
  __shared__ float tile[32][33];
  const int bx = blockIdx.x;
  const int t = threadIdx.x;
  if (bx < 4096) {
    size_t i = ((size_t)bx * 256 + t) * 8;
    float4 a = *(const float4*)(x + i);
    float4 b = *(const float4*)(x + i + 4);
    uint4 o;
    o.x = (uint32_t)f2bf(a.x) | ((uint32_t)f2bf(a.y) << 16);
    o.y = (uint32_t)f2bf(a.z) | ((uint32_t)f2bf(a.w) << 16);
    o.z = (uint32_t)f2bf(b.x) | ((uint32_t)f2bf(b.y) << 16);
    o.w = (uint32_t)f2bf(b.z) | ((uint32_t)f2bf(b.w) << 16);
    *(uint4*)(xb + i) = o;
  } else {
    const int b = bx - 4096;              // 0..3071
    const int z = b >> 10;
    const int rest = b & 1023;
    const int bxx = rest & 31, byy = rest >> 5;
    const float* Wz = W + (size_t)z * 1048576;
    unsigned short* Wtz = Wt + (size_t)z * 1048576;
    const int x0 = bxx * 32, y0 = byy * 32;
    const int tx = t & 31, ty = t >> 5;
#pragma unroll
    for (int i = 0; i < 32; i += 8)
      tile[ty + i][tx] = Wz[(size_t)(y0 + ty + i) * 1024 + x0 + tx];
    __syncthreads();
#pragma unroll
    for (int i = 0; i < 32; i += 8)
      Wtz[(size_t)(x0 + ty + i) * 1024 + y0 + tx] = f2bf(tile[tx][ty + i]);
  }
}

// ---------- GEMM: C[m,n] = A[m,:] . Bt[n,:] ----------
// Tiles 128x128, BK=32, double-buffered LDS (one barrier per K-step; next
// tile's global_load_lds issued before compute so the barrier's vmcnt drain
// has a full compute phase in flight). XOR-swizzled LDS (conflict-free,
// verified R1: SQ_LDS_BANK_CONFLICT 4.2e6 -> 0).
// MODE 4 = merged QKV: z=0,1 -> bf16 C + z*sC; z=2 -> transposed Vt[b][e][s]
// MODE 5 = scores: epilogue exp(acc/32) -> bf16 P_un; per-row partial sums
//          of exp into aux[32][8192] (j = blockIdx.y*2 + wave-col)
// MODE 6 = PV: epilogue out = acc / rowsum (rowsum = sum of 32 partials)
template <int MODE>
__global__ void __launch_bounds__(256)
gemm_bt(const unsigned short* __restrict__ Aall,
        const unsigned short* __restrict__ Btall,
        void* __restrict__ Call, unsigned short* __restrict__ VtPtr,
        float* __restrict__ aux,
        int K, int ldc, long sA, long sB, long sC, float scale) {
  __shared__ unsigned short As[2][4096];
  __shared__ unsigned short Bs[2][4096];
  const int t = threadIdx.x;
  const int lane = t & 63;
  const int quad = lane >> 4;
  const int l15 = lane & 15;
  const int wave = t >> 6;
  const int wm = (wave >> 1) * 64;
  const int wn = (wave & 1) * 64;
  const int z = blockIdx.z;

  const unsigned short* A = Aall + (size_t)z * sA + (size_t)blockIdx.x * 128 * K;
  const unsigned short* Bt = Btall + (size_t)z * sB + (size_t)blockIdx.y * 128 * K;

  const int srow = t >> 2;                             // 0..63
  const int scol = (((t & 3) ^ ((srow >> 1) & 3)) * 8);
  const unsigned short* ga = A + (size_t)srow * K + scol;
  const unsigned short* gb = Bt + (size_t)srow * K + scol;
  const size_t rowskip = (size_t)64 * K;

  const int aOff = (wm + l15) * 32 + (quad ^ ((l15 >> 1) & 3)) * 8;
  const int bOff = (wn + l15) * 32 + (quad ^ ((l15 >> 1) & 3)) * 8;

  f32x4 acc[4][4];
#pragma unroll
  for (int i = 0; i < 4; i++)
#pragma unroll
    for (int j = 0; j < 4; j++) acc[i][j] = (f32x4){0.f, 0.f, 0.f, 0.f};

  gload_lds16(ga, &As[0][t * 8]);
  gload_lds16(ga + rowskip, &As[0][2048 + t * 8]);
  gload_lds16(gb, &Bs[0][t * 8]);
  gload_lds16(gb + rowskip, &Bs[0][2048 + t * 8]);

  int buf = 0;
  for (int k0 = 0; k0 < K; k0 += 32, buf ^= 1) {
    __syncthreads();
    if (k0 + 32 < K) {
      const int kn = k0 + 32;
      gload_lds16(ga + kn, &As[buf ^ 1][t * 8]);
      gload_lds16(ga + rowskip + kn, &As[buf ^ 1][2048 + t * 8]);
      gload_lds16(gb + kn, &Bs[buf ^ 1][t * 8]);
      gload_lds16(gb + rowskip + kn, &Bs[buf ^ 1][2048 + t * 8]);
    }
    const unsigned short* aB = &As[buf][aOff];
    const unsigned short* bB = &Bs[buf][bOff];
    bf16x8 a[4], b[4];
#pragma unroll
    for (int i = 0; i < 4; i++) a[i] = *(const bf16x8*)(aB + i * 512);
#pragma unroll
    for (int j = 0; j < 4; j++) b[j] = *(const bf16x8*)(bB + j * 512);
#pragma unroll
    for (int i = 0; i < 4; i++)
#pragma unroll
      for (int j = 0; j < 4; j++)
        acc[i][j] = __builtin_amdgcn_mfma_f32_16x16x32_bf16(a[i], b[j], acc[i][j], 0, 0, 0);
  }

  // C/D layout: col = lane&15, row = quad*4 + reg  [verified m89/m91]
  const int mbase = blockIdx.x * 128 + wm + quad * 4;
  const int nbase = blockIdx.y * 128 + wn + l15;

  if (MODE == 4) {
    if (z < 2) {
      unsigned short* C = (unsigned short*)Call + (size_t)z * sC;
#pragma unroll
      for (int mi = 0; mi < 4; mi++)
#pragma unroll
        for (int ni = 0; ni < 4; ni++) {
          const int m = mbase + mi * 16, n = nbase + ni * 16;
#pragma unroll
          for (int r = 0; r < 4; r++)
            C[(size_t)(m + r) * ldc + n] = f2bf(acc[mi][ni][r]);
        }
    } else {  // z==2: Vt[b][e=n][s] <- acc, m = b*2048 + s
      unsigned short* C = VtPtr;
#pragma unroll
      for (int mi = 0; mi < 4; mi++) {
        const int m = mbase + mi * 16;
        const int b = m >> 11, s = m & 2047;
#pragma unroll
        for (int ni = 0; ni < 4; ni++) {
          const int n = nbase + ni * 16;
          uint2 val;
          val.x = (uint32_t)f2bf(acc[mi][ni][0]) | ((uint32_t)f2bf(acc[mi][ni][1]) << 16);
          val.y = (uint32_t)f2bf(acc[mi][ni][2]) | ((uint32_t)f2bf(acc[mi][ni][3]) << 16);
          *(uint2*)(C + (size_t)b * 2097152 + (size_t)n * 2048 + s) = val;
        }
      }
    }
  } else if (MODE == 5) {
    // exp + store P_un + per-row partial sums
    unsigned short* C = (unsigned short*)Call + (size_t)z * sC;
    const int j = blockIdx.y * 2 + (wn >> 6);
#pragma unroll
    for (int mi = 0; mi < 4; mi++) {
#pragma unroll
      for (int r = 0; r < 4; r++) {
        const int m = mbase + mi * 16 + r;
        float s = 0.f;
#pragma unroll
        for (int ni = 0; ni < 4; ni++) {
          const float e = __expf(acc[mi][ni][r] * scale);
          C[(size_t)m * ldc + nbase + ni * 16] = f2bf(e);
          s += e;
        }
        s += __shfl_xor(s, 1);
        s += __shfl_xor(s, 2);
        s += __shfl_xor(s, 4);
        s += __shfl_xor(s, 8);
        if (l15 == 0) aux[(size_t)j * 8192 + (size_t)z * 2048 + m] = s;
      }
    }
  } else {  // MODE 6: PV + normalize
    float* C = (float*)Call + (size_t)z * sC;
#pragma unroll
    for (int mi = 0; mi < 4; mi++) {
#pragma unroll
      for (int r = 0; r < 4; r++) {
        const int m = mbase + mi * 16 + r;
        const size_t grow = (size_t)z * 2048 + m;
        float tot = 0.f;
#pragma unroll
        for (int j = 0; j < 32; j++) tot += aux[(size_t)j * 8192 + grow];
        const float inv = 1.f / tot;
#pragma unroll
        for (int ni = 0; ni < 4; ni++)
          C[(size_t)m * ldc + nbase + ni * 16] = acc[mi][ni][r] * inv;
      }
    }
  }
}

// ---------- launcher ----------
// B=4, S=2048, D=1024. Workspace (102 MB):
//   xb @0: 16MB | Wt @16MB: 6MB (dead after QKV; partial[32][8192] overlays it)
//   Q @22MB: 16MB | K @38MB: 16MB | Vt @54MB: 16MB [4][e][s]
//   Sb @70MB: 32MB P_unnorm bf16 [4][2048][2048]
extern "C" void kernel_launch(void* const* d_in, const int* in_sizes, int n_in,
                              void* d_out, int out_size, void* d_ws, size_t ws_size,
                              hipStream_t stream) {
  const float* x = (const float*)d_in[0];
  const float* W = (const float*)d_in[1];
  float* out = (float*)d_out;
  char* ws = (char*)d_ws;
  unsigned short* xb = (unsigned short*)(ws);
  unsigned short* Wt = (unsigned short*)(ws + (16ll << 20));
  float* partial     = (float*)(ws + (16ll << 20));   // overlays Wt after QKV
  unsigned short* Q  = (unsigned short*)(ws + (22ll << 20));
  unsigned short* Kb = (unsigned short*)(ws + (38ll << 20));
  unsigned short* Vt = (unsigned short*)(ws + (54ll << 20));
  unsigned short* Sb = (unsigned short*)(ws + (70ll << 20));

  cast_all<<<7168, 256, 0, stream>>>(x, W, xb, Wt);

  // merged QKV projection: z=0 -> Q, z=1 -> K, z=2 -> Vt (transposed store)
  gemm_bt<4><<<dim3(64, 8, 3), 256, 0, stream>>>(
      xb, Wt, Q, Vt, nullptr, 1024, 1024, 0L, 1048576L, 8388608L, 1.0f);
  // P_un = exp(Q K^T / 32), bf16, + per-row partial sums into `partial`
  gemm_bt<5><<<dim3(16, 16, 4), 256, 0, stream>>>(
      Q, Kb, Sb, nullptr, partial, 1024, 2048, 2097152L, 2097152L, 4194304L, 0.03125f);
  // out = (P_un @ V) / rowsum  (fp32 store to d_out)
  gemm_bt<6><<<dim3(16, 8, 4), 256, 0, stream>>>(
      Sb, Vt, out, nullptr, partial, 2048, 1024, 4194304L, 2097152L, 2097152L, 1.0f);
}